// Round 6
// baseline (202.010 us; speedup 1.0000x reference)
//
#include <hip/hip_runtime.h>
#include <math.h>

#define NB 32
#define NJ 64
#define NC 7
#define NH 128
#define NW 128
#define HW (NH*NW)          // 16384 floats per (b,j)
#define SPLIT 2             // half-scans per (b,j)
#define PART4 (HW/4/SPLIT)  // 2048 float4 per half
#define NSCAN (NB*NJ*SPLIT) // 4096 scan blocks
#define CNTSTRIDE 16        // counters 64 B apart (no line contention)
#define SMOOTHING 0.1f

typedef float f32x4 __attribute__((ext_vector_type(4)));

// Fused kernel. Blocks [0, NSCAN): scan one (b,j,half) -> publish partial,
// release-add per-b counter. Blocks [NSCAN, NSCAN+NB): preload gt row, spin on
// counter b, then merge partials + pred gather + BCE + mean -> out[b].
// Finisher b starts as soon as batch b's 128 partials are published,
// overlapping with the remaining scan instead of a serialized second node.
__global__ __launch_bounds__(256) void labelloss_fused_kernel(
    const float* __restrict__ pred,
    const float* __restrict__ gt,
    const float* __restrict__ heatmap,
    float* __restrict__ wsv,
    int*   __restrict__ wsi,
    int*   __restrict__ cnt,
    float* __restrict__ out)
{
    const int t = threadIdx.x;

    if (blockIdx.x < NSCAN) {
        // ---------------- scan path ----------------
        const int blk  = blockIdx.x;        // (b*NJ + j)*SPLIT + half
        const int bj   = blk >> 1;
        const int half = blk & 1;
        const f32x4* __restrict__ hm4 =
            (const f32x4*)heatmap + (size_t)bj * (HW/4) + (size_t)half * PART4;

        float best    = -INFINITY;
        int   bestIdx = HW;                 // sentinel

        // Per-thread visit order increasing -> strict '>' keeps first-occurrence.
        #pragma unroll
        for (int i = 0; i < PART4/256; ++i) {
            const int i4 = t + (i << 8);
            const f32x4 v = __builtin_nontemporal_load(&hm4[i4]);
            const int base = (half * PART4 + i4) << 2;
            if (v[0] > best) { best = v[0]; bestIdx = base;     }
            if (v[1] > best) { best = v[1]; bestIdx = base + 1; }
            if (v[2] > best) { best = v[2]; bestIdx = base + 2; }
            if (v[3] > best) { best = v[3]; bestIdx = base + 3; }
        }

        // wave-64 reduce (max, tie -> min index)
        #pragma unroll
        for (int off = 32; off > 0; off >>= 1) {
            const float ov = __shfl_down(best, off);
            const int   oi = __shfl_down(bestIdx, off);
            if (ov > best || (ov == best && oi < bestIdx)) { best = ov; bestIdx = oi; }
        }

        __shared__ float sv[4];
        __shared__ int   si[4];
        const int wid  = t >> 6;
        const int lane = t & 63;
        if (lane == 0) { sv[wid] = best; si[wid] = bestIdx; }
        __syncthreads();

        if (t == 0) {
            #pragma unroll
            for (int w = 1; w < 4; ++w) {
                if (sv[w] > best || (sv[w] == best && si[w] < bestIdx)) { best = sv[w]; bestIdx = si[w]; }
            }
            // Publish partial at agent scope (coherent point, cross-XCD safe),
            // then release-add the per-b counter.
            __hip_atomic_store(&wsv[blk], best,    __ATOMIC_RELAXED, __HIP_MEMORY_SCOPE_AGENT);
            __hip_atomic_store(&wsi[blk], bestIdx, __ATOMIC_RELAXED, __HIP_MEMORY_SCOPE_AGENT);
            __hip_atomic_fetch_add(&cnt[(blk >> 7) * CNTSTRIDE], 1,
                                   __ATOMIC_RELEASE, __HIP_MEMORY_SCOPE_AGENT);
        }
    } else {
        // ---------------- finisher path ----------------
        if (t >= NJ) return;                // one wave does the work
        const int b = blockIdx.x - NSCAN;
        const int j = t;

        // Independent read-only loads first: overlap with the spin.
        float td[NC];
        #pragma unroll
        for (int c = 0; c < NC; ++c)
            td[c] = (1.0f - SMOOTHING) * gt[((size_t)b * NJ + j) * NC + c]
                    + SMOOTHING / (float)NC;

        // Spin until all 128 partials of batch b are published.
        while (__hip_atomic_load(&cnt[b * CNTSTRIDE],
                                 __ATOMIC_ACQUIRE, __HIP_MEMORY_SCOPE_AGENT) < NJ * SPLIT)
            __builtin_amdgcn_s_sleep(8);

        const int p0 = (b * NJ + j) * SPLIT;
        const float pv0 = __hip_atomic_load(&wsv[p0],   __ATOMIC_RELAXED, __HIP_MEMORY_SCOPE_AGENT);
        const float pv1 = __hip_atomic_load(&wsv[p0+1], __ATOMIC_RELAXED, __HIP_MEMORY_SCOPE_AGENT);
        const int   pi0 = __hip_atomic_load(&wsi[p0],   __ATOMIC_RELAXED, __HIP_MEMORY_SCOPE_AGENT);
        const int   pi1 = __hip_atomic_load(&wsi[p0+1], __ATOMIC_RELAXED, __HIP_MEMORY_SCOPE_AGENT);

        // Halves in increasing-index order: strict '>' keeps first-occurrence.
        float best    = pv0;
        int   bestIdx = pi0;
        if (pv1 > best) { best = pv1; bestIdx = pi1; }

        const int x = bestIdx >> 7;         // flat // 128
        const int y = bestIdx & 127;        // flat % 128

        float s = 0.0f;
        #pragma unroll
        for (int c = 0; c < NC; ++c) {
            const float z = pred[(((size_t)b * NC + c) * NH + x) * NW + y];
            s += fmaxf(z, 0.0f) - z * td[c] + log1pf(expf(-fabsf(z)));
        }

        #pragma unroll
        for (int off = 32; off > 0; off >>= 1) s += __shfl_down(s, off);
        if (j == 0) out[b] = s * (1.0f / (float)NJ);
    }
}

extern "C" void kernel_launch(void* const* d_in, const int* in_sizes, int n_in,
                              void* d_out, int out_size, void* d_ws, size_t ws_size,
                              hipStream_t stream) {
    const float* pred    = (const float*)d_in[0];
    const float* gt      = (const float*)d_in[1];
    const float* heatmap = (const float*)d_in[2];
    float* out = (float*)d_out;
    float* wsv = (float*)d_ws;                               // 4096 floats @ 0
    int*   wsi = (int*)((char*)d_ws + NSCAN * 4);            // 4096 ints  @ 16 KB
    int*   cnt = (int*)((char*)d_ws + 2 * NSCAN * 4);        // 32 strided @ 32 KB

    // Zero the per-b counters every call (deterministic, graph-legal).
    hipMemsetAsync(cnt, 0, NB * CNTSTRIDE * sizeof(int), stream);
    labelloss_fused_kernel<<<NSCAN + NB, 256, 0, stream>>>(
        pred, gt, heatmap, wsv, wsi, cnt, out);
}

// Round 7
// 27.454 us; speedup vs baseline: 7.3581x; 7.3581x over previous
//
#include <hip/hip_runtime.h>
#include <math.h>

#define NB 32
#define NJ 64
#define NC 7
#define NH 128
#define NW 128
#define HW (NH*NW)          // 16384 floats per (b,j)
#define SPLIT 2             // half-scans per (b,j)
#define PART4 (HW/4/SPLIT)  // 2048 float4 per half
#define SMOOTHING 0.1f

typedef float f32x4 __attribute__((ext_vector_type(4)));

// Kernel 1: one block per (b,j,half). Scans 8192 floats (2048 float4, 8/thread)
// with non-temporal loads (single-touch stream, skip cache allocation), writes
// (maxval, arg flat index) partial to ws. 4096 blocks = 2 generations of waves.
// NOTE (R6 lesson): do NOT fuse the finisher via spin-wait on agent-scope
// atomics — the per-poll acquire/invalidate cost serializes the machine (7x).
__global__ __launch_bounds__(256) void labelloss_scan_kernel(
    const float* __restrict__ heatmap,
    float* __restrict__ wsv,
    int*   __restrict__ wsi)
{
    const int blk  = blockIdx.x;        // (b*NJ + j)*SPLIT + half
    const int bj   = blk >> 1;
    const int half = blk & 1;
    const f32x4* __restrict__ hm4 =
        (const f32x4*)heatmap + (size_t)bj * (HW/4) + (size_t)half * PART4;

    const int t = threadIdx.x;
    float best    = -INFINITY;
    int   bestIdx = HW;                 // sentinel

    // Per-thread visit order is increasing -> strict '>' keeps first-occurrence.
    #pragma unroll
    for (int i = 0; i < PART4/256; ++i) {
        const int i4 = t + (i << 8);
        const f32x4 v = __builtin_nontemporal_load(&hm4[i4]);
        const int base = (half * PART4 + i4) << 2;   // flat index within (b,j)
        if (v[0] > best) { best = v[0]; bestIdx = base;     }
        if (v[1] > best) { best = v[1]; bestIdx = base + 1; }
        if (v[2] > best) { best = v[2]; bestIdx = base + 2; }
        if (v[3] > best) { best = v[3]; bestIdx = base + 3; }
    }

    // wave-64 reduce (max, tie -> min index)
    #pragma unroll
    for (int off = 32; off > 0; off >>= 1) {
        const float ov = __shfl_down(best, off);
        const int   oi = __shfl_down(bestIdx, off);
        if (ov > best || (ov == best && oi < bestIdx)) { best = ov; bestIdx = oi; }
    }

    __shared__ float sv[4];
    __shared__ int   si[4];
    const int wid  = t >> 6;
    const int lane = t & 63;
    if (lane == 0) { sv[wid] = best; si[wid] = bestIdx; }
    __syncthreads();

    if (t == 0) {
        #pragma unroll
        for (int w = 1; w < 4; ++w) {
            if (sv[w] > best || (sv[w] == best && si[w] < bestIdx)) { best = sv[w]; bestIdx = si[w]; }
        }
        wsv[blk] = best;
        wsi[blk] = bestIdx;
    }
}

// Kernel 2: one wave per b. Thread j: issue independent gt loads first, merge
// its 2 partials (vectorized), gather pred at argmax, BCE, wave-reduce mean.
__global__ __launch_bounds__(64) void labelloss_finish_kernel(
    const float* __restrict__ pred,
    const float* __restrict__ gt,
    const float* __restrict__ wsv,
    const int*   __restrict__ wsi,
    float* __restrict__ out)
{
    const int b = blockIdx.x;
    const int j = threadIdx.x;
    const int p0 = (b * NJ + j) * SPLIT;

    // Independent loads first: gt row (7 floats) + partials; only the pred
    // gather is on the dependent (argmax) path.
    float td[NC];
    #pragma unroll
    for (int c = 0; c < NC; ++c)
        td[c] = (1.0f - SMOOTHING) * gt[((size_t)b * NJ + j) * NC + c]
                + SMOOTHING / (float)NC;

    const float2 pv = *(const float2*)(wsv + p0);
    const int2   pi = *(const int2*)(wsi + p0);

    // Halves are in increasing-index order: strict '>' keeps first-occurrence.
    float best    = pv.x;
    int   bestIdx = pi.x;
    if (pv.y > best) { best = pv.y; bestIdx = pi.y; }

    const int x = bestIdx >> 7;         // flat // 128
    const int y = bestIdx & 127;        // flat % 128

    float s = 0.0f;
    #pragma unroll
    for (int c = 0; c < NC; ++c) {
        const float z = pred[(((size_t)b * NC + c) * NH + x) * NW + y];
        s += fmaxf(z, 0.0f) - z * td[c] + log1pf(expf(-fabsf(z)));
    }

    #pragma unroll
    for (int off = 32; off > 0; off >>= 1) s += __shfl_down(s, off);
    if (j == 0) out[b] = s * (1.0f / (float)NJ);
}

extern "C" void kernel_launch(void* const* d_in, const int* in_sizes, int n_in,
                              void* d_out, int out_size, void* d_ws, size_t ws_size,
                              hipStream_t stream) {
    const float* pred    = (const float*)d_in[0];
    const float* gt      = (const float*)d_in[1];
    const float* heatmap = (const float*)d_in[2];
    float* out = (float*)d_out;
    float* wsv = (float*)d_ws;                          // 4096 floats
    int*   wsi = (int*)((char*)d_ws + NB*NJ*SPLIT*4);   // 4096 ints

    labelloss_scan_kernel<<<NB * NJ * SPLIT, 256, 0, stream>>>(heatmap, wsv, wsi);
    labelloss_finish_kernel<<<NB, 64, 0, stream>>>(pred, gt, wsv, wsi, out);
}